// Round 11
// baseline (154.809 us; speedup 1.0000x reference)
//
#include <hip/hip_runtime.h>
#include <hip/hip_bf16.h>

// EmbeddingLoss — ROUND 11 = COUNTER CAPTURE (output still exact).
// R10 structure unchanged; main loop executed 8x (#pragma unroll 1) with
// epilogue scale 2/8 = 0.25f (exact). The amplified gram8 dispatch ranks
// top-1 in rocprof -> first counter read of the conflict-fixed loop.
// dur16 model: f_new = (dur - 82.5)/7 per-pass cost.

#define BN 8192
#define DK 256
#define NT 64                      // BN/128 tiles per dim
#define NBLK (NT * (NT + 1) / 2)   // 2080 upper-tri tiles = 8*260
#define REPS 8

typedef float f32x4 __attribute__((ext_vector_type(4)));
typedef long  lx2   __attribute__((ext_vector_type(2)));

typedef const __attribute__((address_space(1))) void* gas_vp;
typedef __attribute__((address_space(3))) void* las_vp;

// float -> OCP e4m3fn, RTN-even (software; inputs |x| << 448, no NaN/Inf)
static __device__ __forceinline__ unsigned char f2e4m3(float f) {
    unsigned u = __builtin_bit_cast(unsigned, f);
    unsigned s = (u >> 24) & 0x80;
    int e = (int)((u >> 23) & 0xff) - 127;
    unsigned m = u & 0x7fffff;
    if (e < -9) return (unsigned char)s;          // underflow -> +-0
    if (e >= -6) {                                // normal e4m3
        unsigned mant = m >> 20;
        unsigned rest = m & 0xfffff;
        unsigned round = (rest > 0x80000u) || (rest == 0x80000u && (mant & 1));
        unsigned val = ((unsigned)(e + 7) << 3) | mant;
        val += round;
        return (unsigned char)(s | val);
    }
    int shift = -6 - e;                           // subnormal, 1..3
    unsigned full = 0x800000u | m;
    unsigned rb = 20 + shift;
    unsigned mant = full >> rb;
    unsigned rest = full & ((1u << rb) - 1);
    unsigned half = 1u << (rb - 1);
    unsigned round = (rest > half) || (rest == half && (mant & 1));
    mant += round;
    return (unsigned char)(s | mant);
}

// ---- prep: fp32 -> fp8 with k-permutation + fp32 row norms ----------------
__global__ __launch_bounds__(256) void embl_prep(
    const float* __restrict__ E, unsigned char* __restrict__ E8,
    float* __restrict__ sq)
{
    const int lane = threadIdx.x & 63;
    const int wid  = threadIdx.x >> 6;
    const int row  = blockIdx.x * 4 + wid;    // one row per wave
    const float4 v = *(const float4*)(E + row * DK + lane * 4);
    float s = v.x*v.x + v.y*v.y + v.z*v.z + v.w*v.w;
    uchar4 o;
    o.x = f2e4m3(v.x); o.y = f2e4m3(v.y); o.z = f2e4m3(v.z); o.w = f2e4m3(v.w);
    const int h   = lane >> 5;            // K-half
    const int s_  = (lane >> 3) & 3;      // 32-wide k-segment (= MFMA ks)
    const int kg_ = (lane >> 1) & 3;      // 8-wide lane-group slice
    const int b4  = (lane & 1) * 4;       // 4B within the 8B slice
    const int c_  = ((s_ >> 1) << 2) | kg_;
    const int p_  = s_ & 1;
    *(uchar4*)(E8 + row * 256 + h * 128 + c_ * 16 + p_ * 8 + b4) = o;
    #pragma unroll
    for (int off = 32; off > 0; off >>= 1) s += __shfl_xor(s, off, 64);
    if (lane == 0) sq[row] = s;
}

// ---- main: R10 loop x8 (diagnostic amplification) -------------------------
__global__ __launch_bounds__(256, 4) void embl_gram8(
    const unsigned char* __restrict__ E8, const float* __restrict__ sq,
    const int* __restrict__ lab, float* __restrict__ partials)
{
    __shared__ alignas(16) unsigned char As[128 * 128];   // 16KB
    __shared__ alignas(16) unsigned char Bs[128 * 128];   // 16KB
    __shared__ float wpart[4];

    // XCD-aware chunked swizzle, bijective: 2080 = 8 * 260
    const int bid = (blockIdx.x & 7) * 260 + (blockIdx.x >> 3);
    int t = bid, ti = 0, rl = NT;
    while (t >= rl) { t -= rl; --rl; ++ti; }
    const int tj = ti + t;

    const int tid  = threadIdx.x;
    const int lane = tid & 63;
    const int wid  = tid >> 6;
    const int wr   = wid >> 1;          // 0..1 -> 64-row half
    const int wc   = wid & 1;           // 0..1 -> 64-col half

    const int lcol = lane & 15;         // MFMA frag row index
    const int kg   = lane >> 4;         // 0..3 k lane-group
    const int lk7  = lcol & 7;          // read-side XOR key (== row&7)

    const char* E8c = (const char*)E8;
    const int arow = ti * 128;
    const int brow = tj * 128;

#define STAGE(dst, grow, kt)                                                   \
    {                                                                          \
        _Pragma("unroll")                                                      \
        for (int it_ = 0; it_ < 4; ++it_) {                                    \
            const int c_   = it_ * 256 + tid;   /* 0..1023 */                  \
            const int row_ = c_ >> 3;           /* 0..127  */                  \
            const int sch_ = (c_ & 7) ^ (row_ & 7);                            \
            __builtin_amdgcn_global_load_lds(                                  \
                (gas_vp)(E8c + (long)((grow) + row_) * 256 + (kt) * 128 + sch_ * 16), \
                (las_vp)((char*)(dst) + c_ * 16), 16, 0, 0);                   \
        }                                                                      \
    }

#define WAITVM(N)                                                              \
    {                                                                          \
        asm volatile("s_waitcnt vmcnt(" #N ")" ::: "memory");                  \
        __builtin_amdgcn_sched_barrier(0);                                     \
        __builtin_amdgcn_s_barrier();                                          \
        __builtin_amdgcn_sched_barrier(0);                                     \
    }

#define BARRIER()                                                              \
    {                                                                          \
        __builtin_amdgcn_sched_barrier(0);                                     \
        __builtin_amdgcn_s_barrier();                                          \
        __builtin_amdgcn_sched_barrier(0);                                     \
    }

#define LDF(base, R0, p)                                                       \
    (*(const lx2*)((const char*)(base) + (long)((R0) + lcol) * 128 +           \
        ((((p) * 4 + kg) ^ lk7) * 16)))

#define HALF(p)                                                                \
    {                                                                          \
        lx2 a_[4], b_[4];                                                      \
        _Pragma("unroll")                                                      \
        for (int m_ = 0; m_ < 4; ++m_) {                                       \
            a_[m_] = LDF(As, wr * 64 + m_ * 16, p);                            \
            b_[m_] = LDF(Bs, wc * 64 + m_ * 16, p);                            \
        }                                                                      \
        __builtin_amdgcn_s_setprio(1);                                         \
        _Pragma("unroll")                                                      \
        for (int m_ = 0; m_ < 4; ++m_)                                         \
        _Pragma("unroll")                                                      \
        for (int n_ = 0; n_ < 4; ++n_)                                         \
            acc[m_][n_] = __builtin_amdgcn_mfma_f32_16x16x32_fp8_fp8(          \
                a_[m_][0], b_[n_][0], acc[m_][n_], 0, 0, 0);                   \
        _Pragma("unroll")                                                      \
        for (int m_ = 0; m_ < 4; ++m_)                                         \
        _Pragma("unroll")                                                      \
        for (int n_ = 0; n_ < 4; ++n_)                                         \
            acc[m_][n_] = __builtin_amdgcn_mfma_f32_16x16x32_fp8_fp8(          \
                a_[m_][1], b_[n_][1], acc[m_][n_], 0, 0, 0);                   \
        __builtin_amdgcn_s_setprio(0);                                         \
    }

    f32x4 acc[4][4] = {};

    // ======== DIAGNOSTIC: 8 identical self-contained main-loop passes ======
    #pragma unroll 1
    for (int rep = 0; rep < REPS; ++rep) {
        // K-tile 0
        STAGE(As, arow, 0); STAGE(Bs, brow, 0);
        WAITVM(0);                      // t0 landed, all waves
        HALF(0); HALF(1);
        BARRIER();                      // all waves done reading tile 0
        // K-tile 1
        STAGE(As, arow, 1); STAGE(Bs, brow, 1);
        WAITVM(0);
        HALF(0); HALF(1);
        BARRIER();                      // tile 1 consumed (next rep restages)
    }

    // ---- epilogue: acc holds 8x gram; 2/8 = 0.25f exact -------------------
    const int gi0 = arow + wr * 64;
    const int gj0 = brow + wc * 64;
    float lsum = 0.0f;

#define EPI(MASKED)                                                            \
    {                                                                          \
        float sqj_[4]; int lj_[4], jj_[4];                                     \
        _Pragma("unroll")                                                      \
        for (int n_ = 0; n_ < 4; ++n_) {                                       \
            jj_[n_] = gj0 + n_ * 16 + lcol;                                    \
            sqj_[n_] = sq[jj_[n_]]; lj_[n_] = lab[jj_[n_]];                    \
        }                                                                      \
        _Pragma("unroll")                                                      \
        for (int m_ = 0; m_ < 4; ++m_) {                                       \
            const int ibase = gi0 + m_ * 16 + kg * 4;                          \
            _Pragma("unroll")                                                  \
            for (int r_ = 0; r_ < 4; ++r_) {                                   \
                const int i_ = ibase + r_;                                     \
                const float sqi_ = sq[i_]; const int li_ = lab[i_];            \
                _Pragma("unroll")                                              \
                for (int n_ = 0; n_ < 4; ++n_) {                               \
                    const float mse_ =                                         \
                        (sqi_ + sqj_[n_] - 0.25f * acc[m_][n_][r_]) *          \
                        (1.0f / 256.0f);                                       \
                    float v_ = (li_ == lj_[n_]) ? mse_                         \
                                                : fmaxf(0.0f, 1.0f - mse_);    \
                    if (MASKED && i_ >= jj_[n_]) v_ = 0.0f;                    \
                    lsum += v_;                                                \
                }                                                              \
            }                                                                  \
        }                                                                      \
    }

    if (ti == tj) { EPI(1) } else { EPI(0) }

    #pragma unroll
    for (int off = 32; off > 0; off >>= 1) lsum += __shfl_xor(lsum, off, 64);
    if (lane == 0) wpart[wid] = lsum;
    __syncthreads();
    if (tid == 0)
        partials[blockIdx.x] = wpart[0] + wpart[1] + wpart[2] + wpart[3];
}

// ---- final reduce: 2080 partials -> scaled scalar -------------------------
__global__ __launch_bounds__(1024) void embl_reduce(
    const float* __restrict__ partials, float* __restrict__ out)
{
    __shared__ float w[16];
    const int tid  = threadIdx.x;
    const int lane = tid & 63;
    float s = partials[tid] + partials[tid + 1024];
    if (tid < NBLK - 2048) s += partials[tid + 2048];
    #pragma unroll
    for (int off = 32; off > 0; off >>= 1) s += __shfl_xor(s, off, 64);
    if (lane == 0) w[tid >> 6] = s;
    __syncthreads();
    if (tid == 0) {
        float t = 0.0f;
        #pragma unroll
        for (int i = 0; i < 16; ++i) t += w[i];
        const float scale = 1.0f / ((float)BN * (float)(BN - 1));
        *out = t * scale;
    }
}

extern "C" void kernel_launch(void* const* d_in, const int* in_sizes, int n_in,
                              void* d_out, int out_size, void* d_ws, size_t ws_size,
                              hipStream_t stream) {
    const float* E   = (const float*)d_in[0];
    const int*   lab = (const int*)d_in[1];
    float*       out = (float*)d_out;

    unsigned char* E8 = (unsigned char*)d_ws;                             // 2 MiB
    float*         sq = (float*)((char*)d_ws + (size_t)BN * DK);          // 32 KiB
    float*   partials = (float*)((char*)d_ws + (size_t)BN * DK + BN * 4); // 8.3 KB

    embl_prep<<<BN / 4, 256, 0, stream>>>(E, E8, sq);
    embl_gram8<<<NBLK, 256, 0, stream>>>(E8, sq, lab, partials);
    embl_reduce<<<1, 1024, 0, stream>>>(partials, out);
}

// Round 12
// 111.255 us; speedup vs baseline: 1.3915x; 1.3915x over previous
//
#include <hip/hip_runtime.h>
#include <hip/hip_bf16.h>

// EmbeddingLoss: loss = sum_{i<j} [ same ? mse : max(0,1-mse) ] / (B*(B-1))
// Round 12 (from R11 counters: conflicts=0, MfmaUtil=55%, f=11.4us o=14.6us):
//  * MX-scaled mfma_scale_f32_16x16x128_f8f6f4, unit scales (2x fp8 rate,
//    numerically identical; k-block order permutation-safe: A,B same build).
//  * 2 tiles/block (grid 1040): T1K1 staged under T0 epilogue; A-panel
//    reused when ti1==ti0 (T1 computes K1 first). o amortized 2x.
//  * per-wave atomicAdd to partials[tile] (no __syncthreads vmcnt drain).

#define BN 8192
#define DK 256
#define NT 64                      // BN/128 tiles per dim
#define NBLK (NT * (NT + 1) / 2)   // 2080 upper-tri tiles
#define NGRID (NBLK / 2)           // 1040 = 8 * 130

typedef float f32x4 __attribute__((ext_vector_type(4)));
typedef int   i32x4v __attribute__((ext_vector_type(4)));
typedef int   i32x8v __attribute__((ext_vector_type(8)));

typedef const __attribute__((address_space(1))) void* gas_vp;
typedef __attribute__((address_space(3))) void* las_vp;

// float -> OCP e4m3fn, RTN-even (software; inputs |x| << 448, no NaN/Inf)
static __device__ __forceinline__ unsigned char f2e4m3(float f) {
    unsigned u = __builtin_bit_cast(unsigned, f);
    unsigned s = (u >> 24) & 0x80;
    int e = (int)((u >> 23) & 0xff) - 127;
    unsigned m = u & 0x7fffff;
    if (e < -9) return (unsigned char)s;          // underflow -> +-0
    if (e >= -6) {                                // normal e4m3
        unsigned mant = m >> 20;
        unsigned rest = m & 0xfffff;
        unsigned round = (rest > 0x80000u) || (rest == 0x80000u && (mant & 1));
        unsigned val = ((unsigned)(e + 7) << 3) | mant;
        val += round;
        return (unsigned char)(s | val);
    }
    int shift = -6 - e;                           // subnormal, 1..3
    unsigned full = 0x800000u | m;
    unsigned rb = 20 + shift;
    unsigned mant = full >> rb;
    unsigned rest = full & ((1u << rb) - 1);
    unsigned half = 1u << (rb - 1);
    unsigned round = (rest > half) || (rest == half && (mant & 1));
    mant += round;
    return (unsigned char)(s | mant);
}

// ---- prep: fp32 -> fp8 (k-permuted) + fp32 row norms + zero partials ------
__global__ __launch_bounds__(256) void embl_prep(
    const float* __restrict__ E, unsigned char* __restrict__ E8,
    float* __restrict__ sq, float* __restrict__ partials)
{
    if (blockIdx.x < 9) {
        const int idx = blockIdx.x * 256 + threadIdx.x;
        if (idx < NBLK) partials[idx] = 0.0f;
    }
    const int lane = threadIdx.x & 63;
    const int wid  = threadIdx.x >> 6;
    const int row  = blockIdx.x * 4 + wid;    // one row per wave
    const float4 v = *(const float4*)(E + row * DK + lane * 4);
    float s = v.x*v.x + v.y*v.y + v.z*v.z + v.w*v.w;
    uchar4 o;
    o.x = f2e4m3(v.x); o.y = f2e4m3(v.y); o.z = f2e4m3(v.z); o.w = f2e4m3(v.w);
    const int h   = lane >> 5;            // K-half (kt)
    const int s_  = (lane >> 3) & 3;      // 32-wide k-segment
    const int kg_ = (lane >> 1) & 3;      // 8-wide lane-group slice
    const int b4  = (lane & 1) * 4;
    const int c_  = ((s_ >> 1) << 2) | kg_;
    const int p_  = s_ & 1;
    *(uchar4*)(E8 + row * 256 + h * 128 + c_ * 16 + p_ * 8 + b4) = o;
    #pragma unroll
    for (int off = 32; off > 0; off >>= 1) s += __shfl_xor(s, off, 64);
    if (lane == 0) sq[row] = s;
}

// ---- main: 2 x (128x128) fp8 gram tiles per block, MX K=128 MFMA ----------
__global__ __launch_bounds__(256, 4) void embl_gram(
    const unsigned char* __restrict__ E8, const float* __restrict__ sq,
    const int* __restrict__ lab, float* __restrict__ partials)
{
    __shared__ alignas(16) unsigned char As[128 * 128];   // 16KB
    __shared__ alignas(16) unsigned char Bs[128 * 128];   // 16KB

    // XCD-aware chunked swizzle, bijective: 1040 = 8 * 130
    const int bid2 = (blockIdx.x & 7) * 130 + (blockIdx.x >> 3);
    const int g0 = bid2 * 2, g1 = g0 + 1;
    int t = g0, ti0 = 0, rl = NT;
    while (t >= rl) { t -= rl; --rl; ++ti0; }
    const int tj0 = ti0 + t;
    int ti1, tj1;
    if (tj0 == NT - 1) { ti1 = ti0 + 1; tj1 = ti1; }
    else               { ti1 = ti0;     tj1 = tj0 + 1; }

    const int tid  = threadIdx.x;
    const int lane = tid & 63;
    const int wid  = tid >> 6;
    const int wr   = wid >> 1;          // 0..1 -> 64-row half
    const int wc   = wid & 1;           // 0..1 -> 64-col half

    const int lcol = lane & 15;         // MFMA frag row index
    const int kg   = lane >> 4;         // 0..3 k lane-group
    const int lk7  = lcol & 7;          // read-side XOR key (== row&7)

    const char* E8c = (const char*)E8;

#define STAGE(dst, grow, kt)                                                   \
    {                                                                          \
        _Pragma("unroll")                                                      \
        for (int it_ = 0; it_ < 4; ++it_) {                                    \
            const int c_   = it_ * 256 + tid;   /* 0..1023 */                  \
            const int row_ = c_ >> 3;           /* 0..127  */                  \
            const int sch_ = (c_ & 7) ^ (row_ & 7);                            \
            __builtin_amdgcn_global_load_lds(                                  \
                (gas_vp)(E8c + (long)((grow) + row_) * 256 + (kt) * 128 + sch_ * 16), \
                (las_vp)((char*)(dst) + c_ * 16), 16, 0, 0);                   \
        }                                                                      \
    }

#define WAITVM0()                                                              \
    {                                                                          \
        asm volatile("s_waitcnt vmcnt(0)" ::: "memory");                       \
        __builtin_amdgcn_sched_barrier(0);                                     \
        __builtin_amdgcn_s_barrier();                                          \
        __builtin_amdgcn_sched_barrier(0);                                     \
    }

#define BARRIER()                                                              \
    {                                                                          \
        __builtin_amdgcn_sched_barrier(0);                                     \
        __builtin_amdgcn_s_barrier();                                          \
        __builtin_amdgcn_sched_barrier(0);                                     \
    }

#define LD16(base, R0, p)                                                      \
    (*(const i32x4v*)((const char*)(base) + (long)((R0) + lcol) * 128 +        \
        ((((p) * 4 + kg) ^ lk7) * 16)))

    // one K-tile (K=128) of MFMA: 24 b128 LDS reads + 16 MX-scaled MFMA
#define MXT()                                                                  \
    {                                                                          \
        i32x8v bV[4];                                                          \
        _Pragma("unroll")                                                      \
        for (int n_ = 0; n_ < 4; ++n_) {                                       \
            i32x4v blo = LD16(Bs, wc * 64 + n_ * 16, 0);                       \
            i32x4v bhi = LD16(Bs, wc * 64 + n_ * 16, 1);                       \
            bV[n_] = __builtin_shufflevector(blo, bhi, 0,1,2,3,4,5,6,7);       \
        }                                                                      \
        __builtin_amdgcn_s_setprio(1);                                         \
        _Pragma("unroll")                                                      \
        for (int m_ = 0; m_ < 4; ++m_) {                                       \
            i32x4v alo = LD16(As, wr * 64 + m_ * 16, 0);                       \
            i32x4v ahi = LD16(As, wr * 64 + m_ * 16, 1);                       \
            i32x8v aV = __builtin_shufflevector(alo, ahi, 0,1,2,3,4,5,6,7);    \
            _Pragma("unroll")                                                  \
            for (int n_ = 0; n_ < 4; ++n_)                                     \
                acc[m_][n_] = __builtin_amdgcn_mfma_scale_f32_16x16x128_f8f6f4(\
                    aV, bV[n_], acc[m_][n_], 0, 0,                             \
                    0, 0x7F7F7F7F, 0, 0x7F7F7F7F);                             \
        }                                                                      \
        __builtin_amdgcn_s_setprio(0);                                         \
    }

    // epilogue: C/D layout col=lane&15, row=(lane>>4)*4+reg; per-wave atomic
#define EPIT(gi0v, gj0v, MASKED, g)                                            \
    {                                                                          \
        float lsum = 0.0f;                                                     \
        float sqj_[4]; int lj_[4], jj_[4];                                     \
        _Pragma("unroll")                                                      \
        for (int n_ = 0; n_ < 4; ++n_) {                                       \
            jj_[n_] = (gj0v) + n_ * 16 + lcol;                                 \
            sqj_[n_] = sq[jj_[n_]]; lj_[n_] = lab[jj_[n_]];                    \
        }                                                                      \
        _Pragma("unroll")                                                      \
        for (int m_ = 0; m_ < 4; ++m_) {                                       \
            const int ibase = (gi0v) + m_ * 16 + kg * 4;                       \
            _Pragma("unroll")                                                  \
            for (int r_ = 0; r_ < 4; ++r_) {                                   \
                const int i_ = ibase + r_;                                     \
                const float sqi_ = sq[i_]; const int li_ = lab[i_];            \
                _Pragma("unroll")                                              \
                for (int n_ = 0; n_ < 4; ++n_) {                               \
                    const float mse_ =                                         \
                        (sqi_ + sqj_[n_] - 2.0f * acc[m_][n_][r_]) *           \
                        (1.0f / 256.0f);                                       \
                    float v_ = (li_ == lj_[n_]) ? mse_                         \
                                                : fmaxf(0.0f, 1.0f - mse_);    \
                    if (MASKED && i_ >= jj_[n_]) v_ = 0.0f;                    \
                    lsum += v_;                                                \
                }                                                              \
            }                                                                  \
        }                                                                      \
        _Pragma("unroll")                                                      \
        for (int off = 32; off > 0; off >>= 1)                                 \
            lsum += __shfl_xor(lsum, off, 64);                                 \
        if (lane == 0) atomicAdd(&partials[(g)], lsum);                        \
    }

    f32x4 acc[4][4] = {};
    const f32x4 zf = {0.0f, 0.0f, 0.0f, 0.0f};

    const int ar0 = ti0 * 128, br0 = tj0 * 128;
    const int ar1 = ti1 * 128, br1 = tj1 * 128;

    // ---- tile 0: K0 then K1 ----
    STAGE(As, ar0, 0); STAGE(Bs, br0, 0);
    WAITVM0();
    MXT();
    BARRIER();                          // done reading K0
    STAGE(As, ar0, 1); STAGE(Bs, br0, 1);
    WAITVM0();
    MXT();                              // acc = full tile 0
    BARRIER();                          // done reading K1; As=A(ti0,K1)

    // ---- transition: T1 computes K1 first (A-panel reuse when ti1==ti0) ---
    if (ti1 != ti0) STAGE(As, ar1, 1);
    STAGE(Bs, br1, 1);
    if (ti0 == tj0) { EPIT(ar0 + wr * 64, br0 + wc * 64, 1, g0) }
    else            { EPIT(ar0 + wr * 64, br0 + wc * 64, 0, g0) }
    #pragma unroll
    for (int m_ = 0; m_ < 4; ++m_)
        #pragma unroll
        for (int n_ = 0; n_ < 4; ++n_) acc[m_][n_] = zf;
    WAITVM0();                          // T1K1 landed everywhere
    MXT();
    BARRIER();                          // done reading K1
    STAGE(As, ar1, 0); STAGE(Bs, br1, 0);
    WAITVM0();
    MXT();                              // acc = full tile 1

    if (ti1 == tj1) { EPIT(ar1 + wr * 64, br1 + wc * 64, 1, g1) }
    else            { EPIT(ar1 + wr * 64, br1 + wc * 64, 0, g1) }
}

// ---- final reduce: 2080 partials -> scaled scalar -------------------------
__global__ __launch_bounds__(1024) void embl_reduce(
    const float* __restrict__ partials, float* __restrict__ out)
{
    __shared__ float w[16];
    const int tid  = threadIdx.x;
    const int lane = tid & 63;
    float s = partials[tid] + partials[tid + 1024];
    if (tid < NBLK - 2048) s += partials[tid + 2048];
    #pragma unroll
    for (int off = 32; off > 0; off >>= 1) s += __shfl_xor(s, off, 64);
    if (lane == 0) w[tid >> 6] = s;
    __syncthreads();
    if (tid == 0) {
        float t = 0.0f;
        #pragma unroll
        for (int i = 0; i < 16; ++i) t += w[i];
        const float scale = 1.0f / ((float)BN * (float)(BN - 1));
        *out = t * scale;
    }
}

extern "C" void kernel_launch(void* const* d_in, const int* in_sizes, int n_in,
                              void* d_out, int out_size, void* d_ws, size_t ws_size,
                              hipStream_t stream) {
    const float* E   = (const float*)d_in[0];
    const int*   lab = (const int*)d_in[1];
    float*       out = (float*)d_out;

    unsigned char* E8 = (unsigned char*)d_ws;                             // 2 MiB
    float*         sq = (float*)((char*)d_ws + (size_t)BN * DK);          // 32 KiB
    float*   partials = (float*)((char*)d_ws + (size_t)BN * DK + BN * 4); // 8.3 KB

    embl_prep<<<BN / 4, 256, 0, stream>>>(E, E8, sq, partials);
    embl_gram<<<NGRID, 256, 0, stream>>>(E8, sq, lab, partials);
    embl_reduce<<<1, 1024, 0, stream>>>(partials, out);
}